// Round 14
// baseline (120.013 us; speedup 1.0000x reference)
//
#include <hip/hip_runtime.h>

typedef unsigned char u8;
typedef unsigned short u16;
typedef u16 u16x4 __attribute__((ext_vector_type(4)));
typedef u16 u16x8 __attribute__((ext_vector_type(8)));
typedef __bf16 bf16x8 __attribute__((ext_vector_type(8)));
typedef float f32x2 __attribute__((ext_vector_type(2)));
typedef float f32x4 __attribute__((ext_vector_type(4)));
typedef long longx2 __attribute__((ext_vector_type(2)));

#define BB 16
#define TT 512
#define EE 768
#define HH 12
#define DD 64
#define LL 100
#define BT (BB*TT)             /* 8192 */
#define BTE ((size_t)BT*EE)    /* 6291456 */
#define LOG2E 1.44269504f
#define QSCALE (0.125f*LOG2E)  /* 1/sqrt(D)*log2e, folded into Q projection */
#define FIXMAX 44.0f           /* fixed softmax shift (log2 domain) */

__device__ __forceinline__ float bf2f(u16 u){
  union { float f; unsigned int i; } v; v.i = ((unsigned int)u) << 16; return v.f;
}
__device__ __forceinline__ u16 f2bf(float f){
  __bf16 h = (__bf16)f;
  union { __bf16 h; u16 u; } v; v.h = h; return v.u;
}
// fp8 e4m3 (OCP on gfx950) pack/unpack via HW cvt
__device__ __forceinline__ u16 pk_fp8(float a, float b){
  return (u16)(__builtin_amdgcn_cvt_pk_fp8_f32(a, b, 0, false) & 0xffff);
}
__device__ __forceinline__ u8 f2fp8(float a){
  return (u8)(__builtin_amdgcn_cvt_pk_fp8_f32(a, 0.f, 0, false) & 0xff);
}

// async 16B global->LDS DMA. LDS dest = wave-uniform base + lane*16.
__device__ __forceinline__ void gload16(const void* g, void* l){
  __builtin_amdgcn_global_load_lds(
      (const __attribute__((address_space(1))) void*)g,
      (__attribute__((address_space(3))) void*)l, 16, 0, 0);
}

// ---------------------------------------------------------------------------
// Merged prep: blocks 0-575 transpose+cast W[4] into FP8 [N][K];
// blocks 576-959 build TEb[128][768] / TEt[768][128] bf16; 960-991 mask bias.
// ---------------------------------------------------------------------------
__global__ __launch_bounds__(256,1) void prep_all_kernel(
    const float* __restrict__ Wq, const float* __restrict__ Wk,
    const float* __restrict__ Wv, const float* __restrict__ Wo,
    u8* __restrict__ WT8,
    const float* __restrict__ TE, u16* __restrict__ TEb, u16* __restrict__ TEt,
    const float* __restrict__ mask, float* __restrict__ MBg)
{
  __shared__ float tile[64][65];
  int bx = blockIdx.x;
  int tid = threadIdx.x;
  if (bx < 576){
    int m  = bx / 144, t = bx % 144;
    int tr = t / 12,  tc = t % 12;
    const float* W = (m==0)?Wq : (m==1)?Wk : (m==2)?Wv : Wo;
    u8* dst = WT8 + (size_t)m * EE * EE;
#pragma unroll
    for (int i=0;i<16;i++){
      int idx = tid + 256*i; int r = idx>>6, c = idx&63;
      tile[r][c] = W[(size_t)(tr*64+r)*EE + tc*64 + c];
    }
    __syncthreads();
    // dst[n][k] = W[k][n] in fp8, packed pairs along k
#pragma unroll
    for (int i=0;i<8;i++){
      int idx = tid + 256*i;          // 2048 = 64 r x 32 col-pairs
      int r = idx >> 5, cp = idx & 31;
      u16 pk = pk_fp8(tile[cp*2][r], tile[cp*2+1][r]);
      *(u16*)&dst[(size_t)(tc*64+r)*EE + tr*64 + cp*2] = pk;
    }
  } else if (bx < 960){
    int e = (bx - 576)*2 + (tid >> 7);
    int c = tid & 127;
    u16 v = 0;
    if (c < LL) v = f2bf(TE[(size_t)c*EE + e]);
    TEt[(size_t)e*128 + c] = v;
    if (e < 128){
#pragma unroll
      for (int k=c; k<EE; k+=128)
        TEb[(size_t)e*EE + k] = (e < LL) ? f2bf(TE[(size_t)e*EE + k]) : (u16)0;
    }
  } else {
    int i = (bx - 960)*256 + tid;
    MBg[i] = (1.0f - mask[i]) * (-1e9f * LOG2E) - FIXMAX;
  }
}

// ---------------------------------------------------------------------------
// K1 v2: label scores + softmax, LDS-free (unchanged).
// ---------------------------------------------------------------------------
__global__ __launch_bounds__(64) void label_scores_kernel(
    const float* __restrict__ X, const u16* __restrict__ TEb,
    float* __restrict__ scores_out, u16* __restrict__ att)
{
  int m0 = blockIdx.x * 16;
  int lane = threadIdx.x;
  int l15 = lane & 15, g = lane >> 4;

  const float* xrow = X + (size_t)(m0 + l15)*EE;
  f32x4 s[7] = {};
  for (int k0=0; k0<EE; k0+=64){
    bf16x8 af[2];
#pragma unroll
    for (int kk=0;kk<2;kk++){
      const float* src = xrow + k0 + kk*32 + g*8;
      float4 a = *(const float4*)src, b = *(const float4*)(src+4);
      bf16x8 o;
      o[0]=(__bf16)a.x; o[1]=(__bf16)a.y; o[2]=(__bf16)a.z; o[3]=(__bf16)a.w;
      o[4]=(__bf16)b.x; o[5]=(__bf16)b.y; o[6]=(__bf16)b.z; o[7]=(__bf16)b.w;
      af[kk] = o;
    }
#pragma unroll
    for (int nt=0;nt<7;nt++){
      bf16x8 b0 = *(const bf16x8*)&TEb[(size_t)(nt*16+l15)*EE + k0 + g*8];
      bf16x8 b1 = *(const bf16x8*)&TEb[(size_t)(nt*16+l15)*EE + k0 + 32 + g*8];
      s[nt] = __builtin_amdgcn_mfma_f32_16x16x32_bf16(af[0], b0, s[nt], 0,0,0);
      s[nt] = __builtin_amdgcn_mfma_f32_16x16x32_bf16(af[1], b1, s[nt], 0,0,0);
    }
  }

  int rowb = m0 + g*4;
#pragma unroll
  for (int nt=0;nt<7;nt++){
    int col = nt*16 + l15;
    if (col < LL){
#pragma unroll
      for (int r=0;r<4;r++)
        scores_out[(size_t)(rowb + r)*LL + col] = s[nt][r];
    }
  }
  if (l15 >= 4){
#pragma unroll
    for (int r=0;r<4;r++) s[6][r] = -1e30f;
  }
  float inv[4];
#pragma unroll
  for (int r=0;r<4;r++){
    float tm = s[0][r];
#pragma unroll
    for (int nt=1;nt<7;nt++) tm = fmaxf(tm, s[nt][r]);
    tm = fmaxf(tm, __shfl_xor(tm, 1, 16));
    tm = fmaxf(tm, __shfl_xor(tm, 2, 16));
    tm = fmaxf(tm, __shfl_xor(tm, 4, 16));
    tm = fmaxf(tm, __shfl_xor(tm, 8, 16));
    float ps = 0.f;
#pragma unroll
    for (int nt=0;nt<7;nt++){
      float p = exp2f((s[nt][r] - tm) * LOG2E);
      s[nt][r] = p; ps += p;
    }
    ps += __shfl_xor(ps, 1, 16);
    ps += __shfl_xor(ps, 2, 16);
    ps += __shfl_xor(ps, 4, 16);
    ps += __shfl_xor(ps, 8, 16);
    inv[r] = 1.f/ps;
  }
#pragma unroll
  for (int nt=0;nt<7;nt++){
    int col = nt*16 + l15;
#pragma unroll
    for (int r=0;r<4;r++)
      att[(size_t)(rowb + r)*128 + col] = f2bf(s[nt][r] * inv[r]);
  }
  {
    int col = 112 + l15;
#pragma unroll
    for (int r=0;r<4;r++) att[(size_t)(rowb + r)*128 + col] = 0;
  }
}

// ---------------------------------------------------------------------------
// fle GEMM (bf16 interior, K=128): HT8 = fp8(X+acc), HU8 = fp8(X+tp).
// ---------------------------------------------------------------------------
__global__ __launch_bounds__(256,1) void gemm_fle_kernel(
    const u16* __restrict__ A, const u16* __restrict__ BTw,
    const float* __restrict__ Xf, const float* __restrict__ tp,
    u8* __restrict__ HT8, u8* __restrict__ HU8, int N, int K)
{
  __shared__ u16 As[128*40];
  __shared__ u16 Bs[128*40];
  int nb = N >> 7;
  int m0 = (blockIdx.x / nb) << 7;
  int n0 = (blockIdx.x % nb) << 7;
  int tid  = threadIdx.x, lane = tid & 63, w = tid >> 6;
  int wm = (w >> 1) << 6, wn = (w & 1) << 6;
  int lr = lane & 15, lk = (lane >> 4) << 3;

  f32x4 acc[4][4] = {};

  for (int k0 = 0; k0 < K; k0 += 32){
    __syncthreads();
#pragma unroll
    for (int i=0;i<2;i++){
      int idx = tid + (i<<8);
      int row = idx >> 2, kq = (idx & 3) << 3;
      *(u16x8*)&As[row*40 + kq] = *(const u16x8*)&A  [(size_t)(m0+row)*K + k0 + kq];
      *(u16x8*)&Bs[row*40 + kq] = *(const u16x8*)&BTw[(size_t)(n0+row)*K + k0 + kq];
    }
    __syncthreads();
    bf16x8 af[4], bfr[4];
#pragma unroll
    for (int i=0;i<4;i++) af [i] = *(const bf16x8*)&As[(wm + i*16 + lr)*40 + lk];
#pragma unroll
    for (int j=0;j<4;j++) bfr[j] = *(const bf16x8*)&Bs[(wn + j*16 + lr)*40 + lk];
#pragma unroll
    for (int i=0;i<4;i++)
#pragma unroll
      for (int j=0;j<4;j++)
        acc[i][j] = __builtin_amdgcn_mfma_f32_16x16x32_bf16(af[i], bfr[j], acc[i][j], 0, 0, 0);
  }

  int rbase = (lane >> 4) << 2;
#pragma unroll
  for (int j=0;j<4;j++){
    int col = n0 + wn + j*16 + lr;
    float tpv = tp[col];
#pragma unroll
    for (int i=0;i<4;i++){
#pragma unroll
      for (int r=0;r<4;r++){
        int row = m0 + wm + i*16 + rbase + r;
        float x = Xf[(size_t)row*EE + col];
        HT8[(size_t)row*EE + col] = f2fp8(x + acc[i][j][r]);
        HU8[(size_t)row*EE + col] = f2fp8(x + tpv);
      }
    }
  }
}

// ---------------------------------------------------------------------------
// gemm8 v3: FP8 projection GEMM, k-permutation frag reads (R13, 0 conflicts),
// NOW double-buffered with COUNTED vmcnt + raw s_barrier (T4 / m139 pattern).
// Key insight from R6/R9/R10 failures: __syncthreads lowers to vmcnt(0) which
// drains the just-issued prefetch, making any dbuf = single-buffer minus
// occupancy. Fix: raw __builtin_amdgcn_s_barrier() + asm s_waitcnt vmcnt(8)
// (per wave: 8 DMA loads/buffer; wait oldest 8, keep newest 8 in flight).
// fp8 dbuf = 64KB LDS -> still 2 blocks/CU (same as measured single-buf occ).
// lgkm safety: every ds_read is consumed by an MFMA (compiler lgkmcnt) before
// the second barrier, so reads complete before any overwrite. sched_barrier(0)
// after each wait (rule #18). Drain vmcnt(0) only at the last step.
// Outstanding-count trace: 16 -> (wait 8, +8) x4 -> 8 -> 0.
// FUSED=1: QKV, NB=18 (Q scaled by QSCALE; V written transposed per head).
// ---------------------------------------------------------------------------
template<int NB, int FUSED>
__global__ __launch_bounds__(256,2) void gemm8_kernel(
    const u8* __restrict__ A0, const u8* __restrict__ A1,
    const u8* __restrict__ Wb,
    const float* __restrict__ b0, const float* __restrict__ b1,
    const float* __restrict__ b2,
    u16* __restrict__ C0, u16* __restrict__ C1, u16* __restrict__ C2)
{
  __shared__ __align__(16) u8 As[2][128*128];
  __shared__ __align__(16) u8 Bs[2][128*128];
  const int K = EE;   // bytes per row (1B/elt)

  int nwg = gridDim.x;
  int bid = blockIdx.x;
  int cpx = nwg >> 3;
  int swz = (bid & 7) * cpx + (bid >> 3);
  int mb = swz / NB, nb = swz % NB;
  int m0 = mb << 7;
  int n0 = (FUSED ? (nb % 6) : nb) << 7;

  int which = FUSED ? (nb / 6) : 0;
  const u8* Ap; const u8* Wp; const float* bp; u16* Cp;
  if (!FUSED){ Ap = A0; Wp = Wb; bp = b0; Cp = C0; }
  else {
    if (which == 0){ Ap = A0; Wp = Wb;                      bp = b0; Cp = C0; }
    else if (which == 1){ Ap = A1; Wp = Wb + (size_t)EE*EE; bp = b1; Cp = C1; }
    else { Ap = A1; Wp = Wb + 2*(size_t)EE*EE;              bp = b2; Cp = C2; }
  }

  int tid = threadIdx.x, lane = tid & 63, w = tid >> 6;
  int wm = (w >> 1) << 6, wn = (w & 1) << 6;
  int lr = lane & 15, g = lane >> 4;
  int lrow = lane >> 3;
  int lchunk = (lane & 7) ^ lrow;          // source pre-swizzle (rule #21)

  f32x4 acc[4][4] = {};

#define GST(buf, k0)                                                            \
  { _Pragma("unroll")                                                           \
    for (int t=0;t<4;t++){                                                      \
      int r0 = w*32 + t*8;                                                      \
      gload16(&Ap[(size_t)(m0 + r0 + lrow)*K + (k0) + (lchunk<<4)], &As[buf][r0*128]); \
      gload16(&Wp[(size_t)(n0 + r0 + lrow)*K + (k0) + (lchunk<<4)], &Bs[buf][r0*128]); } }

  GST(0, 0);
  GST(1, 128);

#pragma unroll
  for (int ks = 0; ks < 6; ks++){
    int buf = ks & 1;
    if (ks == 5) { asm volatile("s_waitcnt vmcnt(0)" ::: "memory"); }
    else         { asm volatile("s_waitcnt vmcnt(8)" ::: "memory"); }
    __builtin_amdgcn_sched_barrier(0);
    __builtin_amdgcn_s_barrier();          // buf[ks&1] visible to all waves
#pragma unroll
    for (int t=0;t<2;t++){
      int cs = ((t<<2) + g) ^ (lr & 7);    // 16B chunk; zero-conflict pattern
      longx2 af[4], bfr[4];
#pragma unroll
      for (int i=0;i<4;i++) af [i] = *(const longx2*)&As[buf][(wm + i*16 + lr)*128 + (cs<<4)];
#pragma unroll
      for (int j=0;j<4;j++) bfr[j] = *(const longx2*)&Bs[buf][(wn + j*16 + lr)*128 + (cs<<4)];
#pragma unroll
      for (int i=0;i<4;i++)
#pragma unroll
        for (int j=0;j<4;j++){
          acc[i][j] = __builtin_amdgcn_mfma_f32_16x16x32_fp8_fp8(af[i][0], bfr[j][0], acc[i][j], 0, 0, 0);
          acc[i][j] = __builtin_amdgcn_mfma_f32_16x16x32_fp8_fp8(af[i][1], bfr[j][1], acc[i][j], 0, 0, 0);
        }
    }
    __builtin_amdgcn_s_barrier();          // all waves done reading buf
    if (ks < 4) GST(buf, (ks << 7) + 256); // refill drained buffer, stays in flight
  }
#undef GST

  int rbase = (lane >> 4) << 2;
  float scq = (FUSED && which==0) ? QSCALE : 1.0f;
#pragma unroll
  for (int j=0;j<4;j++){
    int col = n0 + wn + j*16 + lr;
    float bv = bp[col];
    if (FUSED && which == 2){
      int hh = col >> 6, d = col & 63;
#pragma unroll
      for (int i=0;i<4;i++){
        int row0 = m0 + wm + i*16 + rbase;
        int bb = row0 >> 9, t0 = row0 & 511;
        u16x4 o;
#pragma unroll
        for (int r=0;r<4;r++) o[r] = f2bf(acc[i][j][r] + bv);
        *(u16x4*)&Cp[((size_t)(bb*HH + hh)*DD + d)*TT + t0] = o;
      }
    } else {
#pragma unroll
      for (int i=0;i<4;i++){
#pragma unroll
        for (int r=0;r<4;r++){
          int row = m0 + wm + i*16 + rbase + r;
          Cp[(size_t)row*EE + col] = f2bf((acc[i][j][r] + bv) * scq);
        }
      }
    }
  }
}

// ---------------------------------------------------------------------------
// K4: MFMA flash attention v4 — fixed-max softmax, bf16 (unchanged from R13).
// CTX written as fp8 for the O projection.
// ---------------------------------------------------------------------------
__global__ __launch_bounds__(256,3) void attn_mfma_kernel(
    const u16* __restrict__ Q, const u16* __restrict__ K,
    const u16* __restrict__ VT, const float* __restrict__ MBg,
    u8* __restrict__ CTX8)
{
  __shared__ u16 Ks [2][64*64];
  __shared__ u16 VTs[2][64*64];
  __shared__ u16 Pl [4][32*72];

  int bx = blockIdx.x;
  int bh = bx % (BB*HH), q0 = (bx / (BB*HH)) << 7;
  int b = bh / HH, h = bh % HH;
  int tid = threadIdx.x, lane = tid & 63, w = tid >> 6;
  int l15 = lane & 15, g = lane >> 4;
  int wq0 = q0 + w*32;
  size_t rowbase = (size_t)b*TT;
  u16* pw = &Pl[w][0];
  const u16* Kbh = K  + rowbase*EE + h*DD;
  const u16* Vbh = VT + (size_t)bh*DD*TT;
  int lrow = lane >> 3, lchunk = (lane & 7) ^ (lane >> 3);

  bf16x8 qf[2][2];
#pragma unroll
  for (int i=0;i<2;i++)
#pragma unroll
    for (int kk=0;kk<2;kk++)
      qf[i][kk] = *(const bf16x8*)&Q[(rowbase + wq0 + i*16 + l15)*EE + h*DD + kk*32 + g*8];

  f32x4 ctxf[2][4] = {};
  float lrun[2][4] = {};

#define STAGE(buf, k0)                                                          \
  { _Pragma("unroll")                                                           \
    for (int it=0; it<2; ++it){                                                 \
      int r0 = w*16 + it*8;                                                     \
      gload16(&Kbh[(size_t)((k0) + r0 + lrow)*EE + (lchunk<<3)], &Ks [buf][r0*64]); \
      gload16(&Vbh[(size_t)(r0 + lrow)*TT + (k0) + (lchunk<<3)], &VTs[buf][r0*64]); } }

  STAGE(0, 0);

  for (int kt=0; kt<8; ++kt){
    int k0 = kt << 6;
    int buf = kt & 1;
    __syncthreads();

    // mb loads FIRST (older than stage loads -> compiler waits vmcnt(4))
    float mb[4];
#pragma unroll
    for (int kb=0;kb<4;kb++) mb[kb] = MBg[rowbase + k0 + kb*16 + l15];

    if (kt < 7) STAGE(buf^1, k0+64);

    f32x4 s[2][4] = {};
#pragma unroll
    for (int kk=0;kk<2;kk++){
      int cs = ((kk<<2) + g) ^ (l15 & 7);
      bf16x8 kf[4];
#pragma unroll
      for (int kb=0;kb<4;kb++)
        kf[kb] = *(const bf16x8*)&Ks[buf][(kb*16 + l15)*64 + (cs<<3)];
#pragma unroll
      for (int i=0;i<2;i++)
#pragma unroll
        for (int kb=0;kb<4;kb++)
          s[i][kb] = __builtin_amdgcn_mfma_f32_16x16x32_bf16(qf[i][kk], kf[kb], s[i][kb], 0,0,0);
    }

    if ((k0 < wq0 + 32) && (k0 + 64 > wq0)){
#pragma unroll
      for (int i=0;i<2;i++){
        int qr = wq0 + i*16 + g*4;
#pragma unroll
        for (int kb=0;kb<4;kb++){
          int kpos = k0 + kb*16 + l15;
#pragma unroll
          for (int r=0;r<4;r++)
            if (kpos == qr + r) s[i][kb][r] -= 1e9f*LOG2E;
        }
      }
    }

#pragma unroll
    for (int i=0;i<2;i++)
#pragma unroll
      for (int kb=0;kb<4;kb++)
#pragma unroll
        for (int r=0;r<4;r++){
          float p = exp2f(s[i][kb][r] + mb[kb]);
          lrun[i][r] += p;
          pw[(i*16 + g*4 + r)*72 + kb*16 + l15] = f2bf(p);
        }

    bf16x8 pa[2][2];
#pragma unroll
    for (int i=0;i<2;i++)
#pragma unroll
      for (int kk=0;kk<2;kk++)
        pa[i][kk] = *(const bf16x8*)&pw[(i*16 + l15)*72 + kk*32 + g*8];

#pragma unroll
    for (int kk=0;kk<2;kk++){
      int cs = ((kk<<2) + g) ^ (l15 & 7);
      bf16x8 vf[4];
#pragma unroll
      for (int dj=0;dj<4;dj++)
        vf[dj] = *(const bf16x8*)&VTs[buf][(dj*16 + l15)*64 + (cs<<3)];
#pragma unroll
      for (int i=0;i<2;i++)
#pragma unroll
        for (int dj=0;dj<4;dj++)
          ctxf[i][dj] = __builtin_amdgcn_mfma_f32_16x16x32_bf16(pa[i][kk], vf[dj], ctxf[i][dj], 0,0,0);
    }
  }
#undef STAGE

  float inv[2][4];
#pragma unroll
  for (int i=0;i<2;i++)
#pragma unroll
    for (int r=0;r<4;r++){
      float l = lrun[i][r];
      l += __shfl_xor(l, 1, 16);
      l += __shfl_xor(l, 2, 16);
      l += __shfl_xor(l, 4, 16);
      l += __shfl_xor(l, 8, 16);
      inv[i][r] = 1.0f / l;
    }
#pragma unroll
  for (int i=0;i<2;i++)
#pragma unroll
    for (int dj=0;dj<4;dj++)
#pragma unroll
      for (int r=0;r<4;r++)
        pw[(i*16 + g*4 + r)*64 + dj*16 + l15] = f2bf(ctxf[i][dj][r] * inv[i][r]);
#pragma unroll
  for (int t=0;t<4;t++){
    int row = lane >> 1, c = ((lane & 1)<<5) + t*8;
    const u16* pv = &pw[row*64 + c];
    u16x4 o8;
#pragma unroll
    for (int e=0;e<4;e++) o8[e] = pk_fp8(bf2f(pv[2*e]), bf2f(pv[2*e+1]));
    *(u16x4*)&CTX8[(rowbase + wq0 + row)*EE + h*DD + c] = o8;
  }
}

// ---------------------------------------------------------------------------
// K5: LayerNorm(AO + HU)*g + b + HT -> out (f32). HU/HT read as fp8.
// ---------------------------------------------------------------------------
__global__ __launch_bounds__(192,1) void ln_out_kernel(
    const u16* __restrict__ AO, const u8* __restrict__ HU8,
    const u8* __restrict__ HT8, const float* __restrict__ g,
    const float* __restrict__ bta, float* __restrict__ out)
{
  __shared__ float red[3];
  int r = blockIdx.x, tid = threadIdx.x;
  size_t base = (size_t)r*EE;
  int e0 = tid*4;
  u16x4 ao = *(const u16x4*)&AO[base+e0];
  int hu4 = *(const int*)&HU8[base+e0];
  int ht4 = *(const int*)&HT8[base+e0];
  f32x2 hulo = __builtin_amdgcn_cvt_pk_f32_fp8(hu4, false);
  f32x2 huhi = __builtin_amdgcn_cvt_pk_f32_fp8(hu4, true);
  f32x2 htlo = __builtin_amdgcn_cvt_pk_f32_fp8(ht4, false);
  f32x2 hthi = __builtin_amdgcn_cvt_pk_f32_fp8(ht4, true);
  float huv[4] = {hulo[0], hulo[1], huhi[0], huhi[1]};
  float htv[4] = {htlo[0], htlo[1], hthi[0], hthi[1]};
  float x[4];
#pragma unroll
  for (int j=0;j<4;j++) x[j] = bf2f(ao[j]) + huv[j];

  float s = x[0]+x[1]+x[2]+x[3];
#pragma unroll
  for (int o=32;o;o>>=1) s += __shfl_xor(s, o, 64);
  int w = tid>>6;
  if ((tid&63)==0) red[w] = s;
  __syncthreads();
  float mu = (red[0]+red[1]+red[2]) * (1.0f/EE);
  __syncthreads();
  float d2 = 0.f;
#pragma unroll
  for (int j=0;j<4;j++){ float d = x[j]-mu; d2 += d*d; }
#pragma unroll
  for (int o=32;o;o>>=1) d2 += __shfl_xor(d2, o, 64);
  if ((tid&63)==0) red[w] = d2;
  __syncthreads();
  float var = (red[0]+red[1]+red[2]) * (1.0f/EE);
  float rs = rsqrtf(var + 1e-12f);
  float4 gg = *(const float4*)&g[e0];
  float4 bb = *(const float4*)&bta[e0];
  float4 o4;
  o4.x = (x[0]-mu)*rs*gg.x + bb.x + htv[0];
  o4.y = (x[1]-mu)*rs*gg.y + bb.y + htv[1];
  o4.z = (x[2]-mu)*rs*gg.z + bb.z + htv[2];
  o4.w = (x[3]-mu)*rs*gg.w + bb.w + htv[3];
  *(float4*)&out[base+e0] = o4;
}

// ---------------------------------------------------------------------------
extern "C" void kernel_launch(void* const* d_in, const int* in_sizes, int n_in,
                              void* d_out, int out_size, void* d_ws, size_t ws_size,
                              hipStream_t stream)
{
  (void)in_sizes; (void)n_in; (void)out_size; (void)ws_size;
  const float* X    = (const float*)d_in[0];
  const float* mask = (const float*)d_in[1];
  const float* TE   = (const float*)d_in[2];
  const float* tp   = (const float*)d_in[3];
  const float* Wq   = (const float*)d_in[4];
  const float* bq   = (const float*)d_in[5];
  const float* Wk   = (const float*)d_in[6];
  const float* bk   = (const float*)d_in[7];
  const float* Wv   = (const float*)d_in[8];
  const float* bv   = (const float*)d_in[9];
  const float* Wo   = (const float*)d_in[10];
  const float* bo   = (const float*)d_in[11];
  const float* ln_g = (const float*)d_in[12];
  const float* ln_b = (const float*)d_in[13];

  float* out    = (float*)d_out;
  float* scores = out + BTE;

  char* p = (char*)d_ws;
  u8*  HT8  = (u8*)p;  p += BTE;                 // fp8 [8192][768]
  u8*  HU8  = (u8*)p;  p += BTE;
  u8*  CTX8 = (u8*)p;  p += BTE;
  u8*  WT8  = (u8*)p;  p += (size_t)4*EE*EE;     // fp8 4x[768][768] transposed
  u16* Qb   = (u16*)p; p += BTE*2;               // bf16
  u16* Kb   = (u16*)p; p += BTE*2;
  u16* VTb  = (u16*)p; p += BTE*2;               // bf16 [bh*64+d][512]
  u16* AOb  = (u16*)p; p += BTE*2;
  u16* ATT  = (u16*)p; p += (size_t)BT*128*2;    // bf16 [8192][128]
  u16* TEb  = (u16*)p; p += (size_t)128*EE*2;
  u16* TEt  = (u16*)p; p += (size_t)EE*128*2;
  float* MBg = (float*)p;

  prep_all_kernel<<<dim3(992), dim3(256), 0, stream>>>(
      Wq, Wk, Wv, Wo, WT8, TE, TEb, TEt, mask, MBg);

  label_scores_kernel<<<dim3(BT/16), dim3(64), 0, stream>>>(X, TEb, scores, ATT);

  // fle GEMM + fused fp8 HT/HU epilogue: M=8192, N=768, K=128
  gemm_fle_kernel<<<dim3((BT/128)*(EE/128)), dim3(256), 0, stream>>>(
      ATT, TEt, X, tp, HT8, HU8, EE, 128);

  // fused QKV projections (fp8 inputs, bf16 outputs): 64 m x 18 n
  gemm8_kernel<18,1><<<dim3(64*18), dim3(256), 0, stream>>>(
      HU8, HT8, WT8, bq, bk, bv, Qb, Kb, VTb);

  attn_mfma_kernel<<<dim3(BB*HH*4), dim3(256), 0, stream>>>(Qb, Kb, VTb, MBg, CTX8);

  // O projection (fp8 inputs): 64 x 6
  gemm8_kernel<6,0><<<dim3(64*6), dim3(256), 0, stream>>>(
      CTX8, nullptr, WT8 + 3*(size_t)EE*EE, bo, nullptr, nullptr, AOb, nullptr, nullptr);

  ln_out_kernel<<<dim3(BT), dim3(192), 0, stream>>>(AOb, HU8, HT8, ln_g, ln_b, out);
}

// Round 16
// 114.662 us; speedup vs baseline: 1.0467x; 1.0467x over previous
//
#include <hip/hip_runtime.h>

typedef unsigned char u8;
typedef unsigned short u16;
typedef u16 u16x4 __attribute__((ext_vector_type(4)));
typedef u16 u16x8 __attribute__((ext_vector_type(8)));
typedef __bf16 bf16x8 __attribute__((ext_vector_type(8)));
typedef float f32x2 __attribute__((ext_vector_type(2)));
typedef float f32x4 __attribute__((ext_vector_type(4)));
typedef long longx2 __attribute__((ext_vector_type(2)));

#define BB 16
#define TT 512
#define EE 768
#define HH 12
#define DD 64
#define LL 100
#define BT (BB*TT)             /* 8192 */
#define BTE ((size_t)BT*EE)    /* 6291456 */
#define LOG2E 1.44269504f
#define QSCALE (0.125f*LOG2E)  /* 1/sqrt(D)*log2e, folded into Q projection */
#define FIXMAX 44.0f           /* fixed softmax shift (log2 domain) */

__device__ __forceinline__ float bf2f(u16 u){
  union { float f; unsigned int i; } v; v.i = ((unsigned int)u) << 16; return v.f;
}
__device__ __forceinline__ u16 f2bf(float f){
  __bf16 h = (__bf16)f;
  union { __bf16 h; u16 u; } v; v.h = h; return v.u;
}
// fp8 e4m3 (OCP on gfx950) pack/unpack via HW cvt
__device__ __forceinline__ u16 pk_fp8(float a, float b){
  return (u16)(__builtin_amdgcn_cvt_pk_fp8_f32(a, b, 0, false) & 0xffff);
}
__device__ __forceinline__ u8 f2fp8(float a){
  return (u8)(__builtin_amdgcn_cvt_pk_fp8_f32(a, 0.f, 0, false) & 0xff);
}

// async 16B global->LDS DMA. LDS dest = wave-uniform base + lane*16.
__device__ __forceinline__ void gload16(const void* g, void* l){
  __builtin_amdgcn_global_load_lds(
      (const __attribute__((address_space(1))) void*)g,
      (__attribute__((address_space(3))) void*)l, 16, 0, 0);
}

// ---------------------------------------------------------------------------
// Merged prep: blocks 0-575 transpose+cast W[4] into FP8 [N][K];
// blocks 576-959 build TEb[128][768] / TEt[768][128] bf16; 960-991 mask bias.
// ---------------------------------------------------------------------------
__global__ __launch_bounds__(256,1) void prep_all_kernel(
    const float* __restrict__ Wq, const float* __restrict__ Wk,
    const float* __restrict__ Wv, const float* __restrict__ Wo,
    u8* __restrict__ WT8,
    const float* __restrict__ TE, u16* __restrict__ TEb, u16* __restrict__ TEt,
    const float* __restrict__ mask, float* __restrict__ MBg)
{
  __shared__ float tile[64][65];
  int bx = blockIdx.x;
  int tid = threadIdx.x;
  if (bx < 576){
    int m  = bx / 144, t = bx % 144;
    int tr = t / 12,  tc = t % 12;
    const float* W = (m==0)?Wq : (m==1)?Wk : (m==2)?Wv : Wo;
    u8* dst = WT8 + (size_t)m * EE * EE;
#pragma unroll
    for (int i=0;i<16;i++){
      int idx = tid + 256*i; int r = idx>>6, c = idx&63;
      tile[r][c] = W[(size_t)(tr*64+r)*EE + tc*64 + c];
    }
    __syncthreads();
    // dst[n][k] = W[k][n] in fp8, packed pairs along k
#pragma unroll
    for (int i=0;i<8;i++){
      int idx = tid + 256*i;          // 2048 = 64 r x 32 col-pairs
      int r = idx >> 5, cp = idx & 31;
      u16 pk = pk_fp8(tile[cp*2][r], tile[cp*2+1][r]);
      *(u16*)&dst[(size_t)(tc*64+r)*EE + tr*64 + cp*2] = pk;
    }
  } else if (bx < 960){
    int e = (bx - 576)*2 + (tid >> 7);
    int c = tid & 127;
    u16 v = 0;
    if (c < LL) v = f2bf(TE[(size_t)c*EE + e]);
    TEt[(size_t)e*128 + c] = v;
    if (e < 128){
#pragma unroll
      for (int k=c; k<EE; k+=128)
        TEb[(size_t)e*EE + k] = (e < LL) ? f2bf(TE[(size_t)e*EE + k]) : (u16)0;
    }
  } else {
    int i = (bx - 960)*256 + tid;
    MBg[i] = (1.0f - mask[i]) * (-1e9f * LOG2E) - FIXMAX;
  }
}

// ---------------------------------------------------------------------------
// K1 v2: label scores + softmax, LDS-free (unchanged).
// ---------------------------------------------------------------------------
__global__ __launch_bounds__(64) void label_scores_kernel(
    const float* __restrict__ X, const u16* __restrict__ TEb,
    float* __restrict__ scores_out, u16* __restrict__ att)
{
  int m0 = blockIdx.x * 16;
  int lane = threadIdx.x;
  int l15 = lane & 15, g = lane >> 4;

  const float* xrow = X + (size_t)(m0 + l15)*EE;
  f32x4 s[7] = {};
  for (int k0=0; k0<EE; k0+=64){
    bf16x8 af[2];
#pragma unroll
    for (int kk=0;kk<2;kk++){
      const float* src = xrow + k0 + kk*32 + g*8;
      float4 a = *(const float4*)src, b = *(const float4*)(src+4);
      bf16x8 o;
      o[0]=(__bf16)a.x; o[1]=(__bf16)a.y; o[2]=(__bf16)a.z; o[3]=(__bf16)a.w;
      o[4]=(__bf16)b.x; o[5]=(__bf16)b.y; o[6]=(__bf16)b.z; o[7]=(__bf16)b.w;
      af[kk] = o;
    }
#pragma unroll
    for (int nt=0;nt<7;nt++){
      bf16x8 b0 = *(const bf16x8*)&TEb[(size_t)(nt*16+l15)*EE + k0 + g*8];
      bf16x8 b1 = *(const bf16x8*)&TEb[(size_t)(nt*16+l15)*EE + k0 + 32 + g*8];
      s[nt] = __builtin_amdgcn_mfma_f32_16x16x32_bf16(af[0], b0, s[nt], 0,0,0);
      s[nt] = __builtin_amdgcn_mfma_f32_16x16x32_bf16(af[1], b1, s[nt], 0,0,0);
    }
  }

  int rowb = m0 + g*4;
#pragma unroll
  for (int nt=0;nt<7;nt++){
    int col = nt*16 + l15;
    if (col < LL){
#pragma unroll
      for (int r=0;r<4;r++)
        scores_out[(size_t)(rowb + r)*LL + col] = s[nt][r];
    }
  }
  if (l15 >= 4){
#pragma unroll
    for (int r=0;r<4;r++) s[6][r] = -1e30f;
  }
  float inv[4];
#pragma unroll
  for (int r=0;r<4;r++){
    float tm = s[0][r];
#pragma unroll
    for (int nt=1;nt<7;nt++) tm = fmaxf(tm, s[nt][r]);
    tm = fmaxf(tm, __shfl_xor(tm, 1, 16));
    tm = fmaxf(tm, __shfl_xor(tm, 2, 16));
    tm = fmaxf(tm, __shfl_xor(tm, 4, 16));
    tm = fmaxf(tm, __shfl_xor(tm, 8, 16));
    float ps = 0.f;
#pragma unroll
    for (int nt=0;nt<7;nt++){
      float p = exp2f((s[nt][r] - tm) * LOG2E);
      s[nt][r] = p; ps += p;
    }
    ps += __shfl_xor(ps, 1, 16);
    ps += __shfl_xor(ps, 2, 16);
    ps += __shfl_xor(ps, 4, 16);
    ps += __shfl_xor(ps, 8, 16);
    inv[r] = 1.f/ps;
  }
#pragma unroll
  for (int nt=0;nt<7;nt++){
    int col = nt*16 + l15;
#pragma unroll
    for (int r=0;r<4;r++)
      att[(size_t)(rowb + r)*128 + col] = f2bf(s[nt][r] * inv[r]);
  }
  {
    int col = 112 + l15;
#pragma unroll
    for (int r=0;r<4;r++) att[(size_t)(rowb + r)*128 + col] = 0;
  }
}

// ---------------------------------------------------------------------------
// fle GEMM (bf16 interior, K=128): HT8 = fp8(X+acc), HU8 = fp8(X+tp).
// ---------------------------------------------------------------------------
__global__ __launch_bounds__(256,1) void gemm_fle_kernel(
    const u16* __restrict__ A, const u16* __restrict__ BTw,
    const float* __restrict__ Xf, const float* __restrict__ tp,
    u8* __restrict__ HT8, u8* __restrict__ HU8, int N, int K)
{
  __shared__ u16 As[128*40];
  __shared__ u16 Bs[128*40];
  int nb = N >> 7;
  int m0 = (blockIdx.x / nb) << 7;
  int n0 = (blockIdx.x % nb) << 7;
  int tid  = threadIdx.x, lane = tid & 63, w = tid >> 6;
  int wm = (w >> 1) << 6, wn = (w & 1) << 6;
  int lr = lane & 15, lk = (lane >> 4) << 3;

  f32x4 acc[4][4] = {};

  for (int k0 = 0; k0 < K; k0 += 32){
    __syncthreads();
#pragma unroll
    for (int i=0;i<2;i++){
      int idx = tid + (i<<8);
      int row = idx >> 2, kq = (idx & 3) << 3;
      *(u16x8*)&As[row*40 + kq] = *(const u16x8*)&A  [(size_t)(m0+row)*K + k0 + kq];
      *(u16x8*)&Bs[row*40 + kq] = *(const u16x8*)&BTw[(size_t)(n0+row)*K + k0 + kq];
    }
    __syncthreads();
    bf16x8 af[4], bfr[4];
#pragma unroll
    for (int i=0;i<4;i++) af [i] = *(const bf16x8*)&As[(wm + i*16 + lr)*40 + lk];
#pragma unroll
    for (int j=0;j<4;j++) bfr[j] = *(const bf16x8*)&Bs[(wn + j*16 + lr)*40 + lk];
#pragma unroll
    for (int i=0;i<4;i++)
#pragma unroll
      for (int j=0;j<4;j++)
        acc[i][j] = __builtin_amdgcn_mfma_f32_16x16x32_bf16(af[i], bfr[j], acc[i][j], 0, 0, 0);
  }

  int rbase = (lane >> 4) << 2;
#pragma unroll
  for (int j=0;j<4;j++){
    int col = n0 + wn + j*16 + lr;
    float tpv = tp[col];
#pragma unroll
    for (int i=0;i<4;i++){
#pragma unroll
      for (int r=0;r<4;r++){
        int row = m0 + wm + i*16 + rbase + r;
        float x = Xf[(size_t)row*EE + col];
        HT8[(size_t)row*EE + col] = f2fp8(x + acc[i][j][r]);
        HU8[(size_t)row*EE + col] = f2fp8(x + tpv);
      }
    }
  }
}

// ---------------------------------------------------------------------------
// gemm8 v4: FP8 projection GEMM. K-loop EXACTLY as R13 (single-buffer,
// 2-barrier, k-permutation b128 frag reads — measured 0 conflicts; all 4
// pipelining variants R6/R9/R10/R14 were null-to-negative -> loop is frozen).
// Epilogue routes C through LDS (Cs[128][132] bf16, reusing As+Bs footprint;
// stride 132 -> 2-way write banks = free, 8B-aligned reads) and emits
// 64B-contiguous quad-lane stores:
//  - Q/K/O: 4 lanes x 16B per row-run  (was 64x scalar 2B stores/thread)
//  - V:     4 lanes x 16B t-runs per (head,d) row (was 16x 8B at 1KB lane
//           stride = one cache line PER LANE, ~8x write amplification)
// FUSED=1: QKV, NB=18 (Q scaled by QSCALE; V written transposed per head).
// ---------------------------------------------------------------------------
template<int NB, int FUSED>
__global__ __launch_bounds__(256,2) void gemm8_kernel(
    const u8* __restrict__ A0, const u8* __restrict__ A1,
    const u8* __restrict__ Wb,
    const float* __restrict__ b0, const float* __restrict__ b1,
    const float* __restrict__ b2,
    u16* __restrict__ C0, u16* __restrict__ C1, u16* __restrict__ C2)
{
  __shared__ __align__(16) u8 smem[33792];   // max(As+Bs=32KB, Cs=33792B)
  u8* As = smem;
  u8* Bs = smem + 16384;
  u16* Cs = (u16*)smem;                      // [128][132] bf16
  const int K = EE;   // bytes per row (1B/elt)

  int nwg = gridDim.x;
  int bid = blockIdx.x;
  int cpx = nwg >> 3;
  int swz = (bid & 7) * cpx + (bid >> 3);
  int mb = swz / NB, nb = swz % NB;
  int m0 = mb << 7;
  int n0 = (FUSED ? (nb % 6) : nb) << 7;

  int which = FUSED ? (nb / 6) : 0;
  const u8* Ap; const u8* Wp; const float* bp; u16* Cp;
  if (!FUSED){ Ap = A0; Wp = Wb; bp = b0; Cp = C0; }
  else {
    if (which == 0){ Ap = A0; Wp = Wb;                      bp = b0; Cp = C0; }
    else if (which == 1){ Ap = A1; Wp = Wb + (size_t)EE*EE; bp = b1; Cp = C1; }
    else { Ap = A1; Wp = Wb + 2*(size_t)EE*EE;              bp = b2; Cp = C2; }
  }

  int tid = threadIdx.x, lane = tid & 63, w = tid >> 6;
  int wm = (w >> 1) << 6, wn = (w & 1) << 6;
  int lr = lane & 15, g = lane >> 4;
  int lrow = lane >> 3;
  int lchunk = (lane & 7) ^ lrow;          // source pre-swizzle (rule #21)

  f32x4 acc[4][4] = {};

  for (int k0 = 0; k0 < K; k0 += 128){
    __syncthreads();
#pragma unroll
    for (int t=0;t<4;t++){
      int r0 = w*32 + t*8;
      gload16(&Ap[(size_t)(m0 + r0 + lrow)*K + k0 + (lchunk<<4)], &As[r0*128]);
      gload16(&Wp[(size_t)(n0 + r0 + lrow)*K + k0 + (lchunk<<4)], &Bs[r0*128]);
    }
    __syncthreads();
#pragma unroll
    for (int t=0;t<2;t++){
      int cs = ((t<<2) + g) ^ (lr & 7);    // 16B chunk; zero-conflict pattern
      longx2 af[4], bfr[4];
#pragma unroll
      for (int i=0;i<4;i++) af [i] = *(const longx2*)&As[(wm + i*16 + lr)*128 + (cs<<4)];
#pragma unroll
      for (int j=0;j<4;j++) bfr[j] = *(const longx2*)&Bs[(wn + j*16 + lr)*128 + (cs<<4)];
#pragma unroll
      for (int i=0;i<4;i++)
#pragma unroll
        for (int j=0;j<4;j++){
          acc[i][j] = __builtin_amdgcn_mfma_f32_16x16x32_fp8_fp8(af[i][0], bfr[j][0], acc[i][j], 0, 0, 0);
          acc[i][j] = __builtin_amdgcn_mfma_f32_16x16x32_fp8_fp8(af[i][1], bfr[j][1], acc[i][j], 0, 0, 0);
        }
    }
  }

  // ---- epilogue via LDS: Cs[row][col], stride 132 ----
  int rbase = (lane >> 4) << 2;
  float scq = (FUSED && which==0) ? QSCALE : 1.0f;
  __syncthreads();                         // all As/Bs reads complete
#pragma unroll
  for (int j=0;j<4;j++){
    int col = wn + j*16 + lr;
    float bv = bp[n0 + col];
#pragma unroll
    for (int i=0;i<4;i++)
#pragma unroll
      for (int r=0;r<4;r++)
        Cs[(wm + i*16 + rbase + r)*132 + col] = f2bf((acc[i][j][r] + bv) * scq);
  }
  __syncthreads();

  if (FUSED && which == 2){
    // V transposed: VT[(bb*HH+hh)*DD+d][t]. 4 lanes cover 64B contiguous t.
    int bb = m0 >> 9, t0 = m0 & 511;
    int colb = tid >> 2;                   // 0..63
    int tq = (tid & 3) << 3;               // 0,8,16,24
#pragma unroll
    for (int c2=0;c2<2;c2++){
      int col = colb + (c2<<6);            // 0..127
      int hh = (n0 + col) >> 6, d = (n0 + col) & 63;
      u16* dst = &Cp[((size_t)(bb*HH + hh)*DD + d)*TT + t0];
#pragma unroll
      for (int s=0;s<4;s++){
        int tt = tq + (s<<5);
        u16x8 v;
#pragma unroll
        for (int e=0;e<8;e++) v[e] = Cs[(tt+e)*132 + col];
        *(u16x8*)&dst[tt] = v;
      }
    }
  } else {
    // Q/K/O row-major: 4 lanes x 16B = 64B contiguous per quad.
#pragma unroll
    for (int p=0;p<2;p++){
      int row = (tid >> 2) + (p<<6);       // 0..127
      int c0 = (tid & 3) << 3;             // 0,8,16,24
      size_t gbase = (size_t)(m0 + row)*EE + n0;
      const u16* src = &Cs[row*132];
#pragma unroll
      for (int s=0;s<4;s++){
        int c = c0 + (s<<5);
        u16x4 lo = *(const u16x4*)&src[c];
        u16x4 hi = *(const u16x4*)&src[c+4];
        u16x8 v;
#pragma unroll
        for (int e=0;e<4;e++){ v[e] = lo[e]; v[e+4] = hi[e]; }
        *(u16x8*)&Cp[gbase + c] = v;
      }
    }
  }
}

// ---------------------------------------------------------------------------
// K4: MFMA flash attention v4 — fixed-max softmax, bf16 (unchanged from R13).
// CTX written as fp8 for the O projection.
// ---------------------------------------------------------------------------
__global__ __launch_bounds__(256,3) void attn_mfma_kernel(
    const u16* __restrict__ Q, const u16* __restrict__ K,
    const u16* __restrict__ VT, const float* __restrict__ MBg,
    u8* __restrict__ CTX8)
{
  __shared__ u16 Ks [2][64*64];
  __shared__ u16 VTs[2][64*64];
  __shared__ u16 Pl [4][32*72];

  int bx = blockIdx.x;
  int bh = bx % (BB*HH), q0 = (bx / (BB*HH)) << 7;
  int b = bh / HH, h = bh % HH;
  int tid = threadIdx.x, lane = tid & 63, w = tid >> 6;
  int l15 = lane & 15, g = lane >> 4;
  int wq0 = q0 + w*32;
  size_t rowbase = (size_t)b*TT;
  u16* pw = &Pl[w][0];
  const u16* Kbh = K  + rowbase*EE + h*DD;
  const u16* Vbh = VT + (size_t)bh*DD*TT;
  int lrow = lane >> 3, lchunk = (lane & 7) ^ (lane >> 3);

  bf16x8 qf[2][2];
#pragma unroll
  for (int i=0;i<2;i++)
#pragma unroll
    for (int kk=0;kk<2;kk++)
      qf[i][kk] = *(const bf16x8*)&Q[(rowbase + wq0 + i*16 + l15)*EE + h*DD + kk*32 + g*8];

  f32x4 ctxf[2][4] = {};
  float lrun[2][4] = {};

#define STAGE(buf, k0)                                                          \
  { _Pragma("unroll")                                                           \
    for (int it=0; it<2; ++it){                                                 \
      int r0 = w*16 + it*8;                                                     \
      gload16(&Kbh[(size_t)((k0) + r0 + lrow)*EE + (lchunk<<3)], &Ks [buf][r0*64]); \
      gload16(&Vbh[(size_t)(r0 + lrow)*TT + (k0) + (lchunk<<3)], &VTs[buf][r0*64]); } }

  STAGE(0, 0);

  for (int kt=0; kt<8; ++kt){
    int k0 = kt << 6;
    int buf = kt & 1;
    __syncthreads();

    // mb loads FIRST (older than stage loads -> compiler waits vmcnt(4))
    float mb[4];
#pragma unroll
    for (int kb=0;kb<4;kb++) mb[kb] = MBg[rowbase + k0 + kb*16 + l15];

    if (kt < 7) STAGE(buf^1, k0+64);

    f32x4 s[2][4] = {};
#pragma unroll
    for (int kk=0;kk<2;kk++){
      int cs = ((kk<<2) + g) ^ (l15 & 7);
      bf16x8 kf[4];
#pragma unroll
      for (int kb=0;kb<4;kb++)
        kf[kb] = *(const bf16x8*)&Ks[buf][(kb*16 + l15)*64 + (cs<<3)];
#pragma unroll
      for (int i=0;i<2;i++)
#pragma unroll
        for (int kb=0;kb<4;kb++)
          s[i][kb] = __builtin_amdgcn_mfma_f32_16x16x32_bf16(qf[i][kk], kf[kb], s[i][kb], 0,0,0);
    }

    if ((k0 < wq0 + 32) && (k0 + 64 > wq0)){
#pragma unroll
      for (int i=0;i<2;i++){
        int qr = wq0 + i*16 + g*4;
#pragma unroll
        for (int kb=0;kb<4;kb++){
          int kpos = k0 + kb*16 + l15;
#pragma unroll
          for (int r=0;r<4;r++)
            if (kpos == qr + r) s[i][kb][r] -= 1e9f*LOG2E;
        }
      }
    }

#pragma unroll
    for (int i=0;i<2;i++)
#pragma unroll
      for (int kb=0;kb<4;kb++)
#pragma unroll
        for (int r=0;r<4;r++){
          float p = exp2f(s[i][kb][r] + mb[kb]);
          lrun[i][r] += p;
          pw[(i*16 + g*4 + r)*72 + kb*16 + l15] = f2bf(p);
        }

    bf16x8 pa[2][2];
#pragma unroll
    for (int i=0;i<2;i++)
#pragma unroll
      for (int kk=0;kk<2;kk++)
        pa[i][kk] = *(const bf16x8*)&pw[(i*16 + l15)*72 + kk*32 + g*8];

#pragma unroll
    for (int kk=0;kk<2;kk++){
      int cs = ((kk<<2) + g) ^ (l15 & 7);
      bf16x8 vf[4];
#pragma unroll
      for (int dj=0;dj<4;dj++)
        vf[dj] = *(const bf16x8*)&VTs[buf][(dj*16 + l15)*64 + (cs<<3)];
#pragma unroll
      for (int i=0;i<2;i++)
#pragma unroll
        for (int dj=0;dj<4;dj++)
          ctxf[i][dj] = __builtin_amdgcn_mfma_f32_16x16x32_bf16(pa[i][kk], vf[dj], ctxf[i][dj], 0,0,0);
    }
  }
#undef STAGE

  float inv[2][4];
#pragma unroll
  for (int i=0;i<2;i++)
#pragma unroll
    for (int r=0;r<4;r++){
      float l = lrun[i][r];
      l += __shfl_xor(l, 1, 16);
      l += __shfl_xor(l, 2, 16);
      l += __shfl_xor(l, 4, 16);
      l += __shfl_xor(l, 8, 16);
      inv[i][r] = 1.0f / l;
    }
#pragma unroll
  for (int i=0;i<2;i++)
#pragma unroll
    for (int dj=0;dj<4;dj++)
#pragma unroll
      for (int r=0;r<4;r++)
        pw[(i*16 + g*4 + r)*64 + dj*16 + l15] = f2bf(ctxf[i][dj][r] * inv[i][r]);
#pragma unroll
  for (int t=0;t<4;t++){
    int row = lane >> 1, c = ((lane & 1)<<5) + t*8;
    const u16* pv = &pw[row*64 + c];
    u16x4 o8;
#pragma unroll
    for (int e=0;e<4;e++) o8[e] = pk_fp8(bf2f(pv[2*e]), bf2f(pv[2*e+1]));
    *(u16x4*)&CTX8[(rowbase + wq0 + row)*EE + h*DD + c] = o8;
  }
}

// ---------------------------------------------------------------------------
// K5: LayerNorm(AO + HU)*g + b + HT -> out (f32). HU/HT read as fp8.
// ---------------------------------------------------------------------------
__global__ __launch_bounds__(192,1) void ln_out_kernel(
    const u16* __restrict__ AO, const u8* __restrict__ HU8,
    const u8* __restrict__ HT8, const float* __restrict__ g,
    const float* __restrict__ bta, float* __restrict__ out)
{
  __shared__ float red[3];
  int r = blockIdx.x, tid = threadIdx.x;
  size_t base = (size_t)r*EE;
  int e0 = tid*4;
  u16x4 ao = *(const u16x4*)&AO[base+e0];
  int hu4 = *(const int*)&HU8[base+e0];
  int ht4 = *(const int*)&HT8[base+e0];
  f32x2 hulo = __builtin_amdgcn_cvt_pk_f32_fp8(hu4, false);
  f32x2 huhi = __builtin_amdgcn_cvt_pk_f32_fp8(hu4, true);
  f32x2 htlo = __builtin_amdgcn_cvt_pk_f32_fp8(ht4, false);
  f32x2 hthi = __builtin_amdgcn_cvt_pk_f32_fp8(ht4, true);
  float huv[4] = {hulo[0], hulo[1], huhi[0], huhi[1]};
  float htv[4] = {htlo[0], htlo[1], hthi[0], hthi[1]};
  float x[4];
#pragma unroll
  for (int j=0;j<4;j++) x[j] = bf2f(ao[j]) + huv[j];

  float s = x[0]+x[1]+x[2]+x[3];
#pragma unroll
  for (int o=32;o;o>>=1) s += __shfl_xor(s, o, 64);
  int w = tid>>6;
  if ((tid&63)==0) red[w] = s;
  __syncthreads();
  float mu = (red[0]+red[1]+red[2]) * (1.0f/EE);
  __syncthreads();
  float d2 = 0.f;
#pragma unroll
  for (int j=0;j<4;j++){ float d = x[j]-mu; d2 += d*d; }
#pragma unroll
  for (int o=32;o;o>>=1) d2 += __shfl_xor(d2, o, 64);
  if ((tid&63)==0) red[w] = d2;
  __syncthreads();
  float var = (red[0]+red[1]+red[2]) * (1.0f/EE);
  float rs = rsqrtf(var + 1e-12f);
  float4 gg = *(const float4*)&g[e0];
  float4 bb = *(const float4*)&bta[e0];
  float4 o4;
  o4.x = (x[0]-mu)*rs*gg.x + bb.x + htv[0];
  o4.y = (x[1]-mu)*rs*gg.y + bb.y + htv[1];
  o4.z = (x[2]-mu)*rs*gg.z + bb.z + htv[2];
  o4.w = (x[3]-mu)*rs*gg.w + bb.w + htv[3];
  *(float4*)&out[base+e0] = o4;
}

// ---------------------------------------------------------------------------
extern "C" void kernel_launch(void* const* d_in, const int* in_sizes, int n_in,
                              void* d_out, int out_size, void* d_ws, size_t ws_size,
                              hipStream_t stream)
{
  (void)in_sizes; (void)n_in; (void)out_size; (void)ws_size;
  const float* X    = (const float*)d_in[0];
  const float* mask = (const float*)d_in[1];
  const float* TE   = (const float*)d_in[2];
  const float* tp   = (const float*)d_in[3];
  const float* Wq   = (const float*)d_in[4];
  const float* bq   = (const float*)d_in[5];
  const float* Wk   = (const float*)d_in[6];
  const float* bk   = (const float*)d_in[7];
  const float* Wv   = (const float*)d_in[8];
  const float* bv   = (const float*)d_in[9];
  const float* Wo   = (const float*)d_in[10];
  const float* bo   = (const float*)d_in[11];
  const float* ln_g = (const float*)d_in[12];
  const float* ln_b = (const float*)d_in[13];

  float* out    = (float*)d_out;
  float* scores = out + BTE;

  char* p = (char*)d_ws;
  u8*  HT8  = (u8*)p;  p += BTE;                 // fp8 [8192][768]
  u8*  HU8  = (u8*)p;  p += BTE;
  u8*  CTX8 = (u8*)p;  p += BTE;
  u8*  WT8  = (u8*)p;  p += (size_t)4*EE*EE;     // fp8 4x[768][768] transposed
  u16* Qb   = (u16*)p; p += BTE*2;               // bf16
  u16* Kb   = (u16*)p; p += BTE*2;
  u16* VTb  = (u16*)p; p += BTE*2;               // bf16 [bh*64+d][512]
  u16* AOb  = (u16*)p; p += BTE*2;
  u16* ATT  = (u16*)p; p += (size_t)BT*128*2;    // bf16 [8192][128]
  u16* TEb  = (u16*)p; p += (size_t)128*EE*2;
  u16* TEt  = (u16*)p; p += (size_t)EE*128*2;
  float* MBg = (float*)p;

  prep_all_kernel<<<dim3(992), dim3(256), 0, stream>>>(
      Wq, Wk, Wv, Wo, WT8, TE, TEb, TEt, mask, MBg);

  label_scores_kernel<<<dim3(BT/16), dim3(64), 0, stream>>>(X, TEb, scores, ATT);

  // fle GEMM + fused fp8 HT/HU epilogue: M=8192, N=768, K=128
  gemm_fle_kernel<<<dim3((BT/128)*(EE/128)), dim3(256), 0, stream>>>(
      ATT, TEt, X, tp, HT8, HU8, EE, 128);

  // fused QKV projections (fp8 inputs, bf16 outputs): 64 m x 18 n
  gemm8_kernel<18,1><<<dim3(64*18), dim3(256), 0, stream>>>(
      HU8, HT8, WT8, bq, bk, bv, Qb, Kb, VTb);

  attn_mfma_kernel<<<dim3(BB*HH*4), dim3(256), 0, stream>>>(Qb, Kb, VTb, MBg, CTX8);

  // O projection (fp8 inputs): 64 x 6
  gemm8_kernel<6,0><<<dim3(64*6), dim3(256), 0, stream>>>(
      CTX8, nullptr, WT8 + 3*(size_t)EE*EE, bo, nullptr, nullptr, AOb, nullptr, nullptr);

  ln_out_kernel<<<dim3(BT), dim3(192), 0, stream>>>(AOb, HU8, HT8, ln_g, ln_b, out);
}